// Round 15
// baseline (176.180 us; speedup 1.0000x reference)
//
#include <hip/hip_runtime.h>
#include <hip/hip_bf16.h>

// Shapes
#define B_ 64
#define L_ 64
#define D_ 512
#define F_ 32
#define H_ 512
#define M_ROWS 2048
#define M2 2112
#define KA 1024

typedef __attribute__((ext_vector_type(8))) short bf16x8;
typedef __attribute__((ext_vector_type(4))) float f32x4;

__device__ __forceinline__ float leaky(float v) { return v > 0.0f ? v : 0.01f * v; }

__device__ __forceinline__ unsigned short f2bf(float v) {
  unsigned int b = __float_as_uint(v);
  unsigned int r = b + 0x7FFF + ((b >> 16) & 1);  // RNE
  return (unsigned short)(r >> 16);
}
__device__ __forceinline__ float bf2f(unsigned short h) {
  return __uint_as_float(((unsigned int)h) << 16);
}
__device__ __forceinline__ void cvt_store4(unsigned short* ph, unsigned short* pl, float4 v) {
  ushort4 h, l;
  h.x = f2bf(v.x); l.x = f2bf(v.x - bf2f(h.x));
  h.y = f2bf(v.y); l.y = f2bf(v.y - bf2f(h.y));
  h.z = f2bf(v.z); l.z = f2bf(v.z - bf2f(h.z));
  h.w = f2bf(v.w); l.w = f2bf(v.w - bf2f(h.w));
  *(ushort4*)ph = h;
  *(ushort4*)pl = l;
}

#define GLOAD16(GP, LP)                                              \
  __builtin_amdgcn_global_load_lds(                                  \
      (const __attribute__((address_space(1))) unsigned int*)(GP),   \
      (__attribute__((address_space(3))) unsigned int*)(LP), 16, 0, 0)

// ---------------- Kernel 1: prep (EXACT R13 + counter zeroing) --------------
__global__ __launch_bounds__(256) void prep(
    const float* __restrict__ x, const int* __restrict__ idx1,
    const int* __restrict__ idx2,
    const float* __restrict__ Ws0, const float* __restrict__ Wa0,
    const float* __restrict__ Ws1, const float* __restrict__ Wa1,
    unsigned short* __restrict__ Xhi, unsigned short* __restrict__ Xlo,
    unsigned short* __restrict__ Mh, unsigned short* __restrict__ Ml,
    unsigned short* __restrict__ W0thi, unsigned short* __restrict__ W0tlo,
    unsigned short* __restrict__ W1thi, unsigned short* __restrict__ W1tlo,
    unsigned int* __restrict__ g1cnt) {
  __shared__ __align__(16) char smem[33024];
  const int blk = blockIdx.x;
  const int t = threadIdx.x;

  if (blk < 512) {
    if (blk == 0) {  // zero split-K semaphores (528) each call
      for (int p = t; p < 528; p += 256) g1cnt[p] = 0u;
    }
    const int base = blk * 256 + t;
#pragma unroll
    for (int i = 0; i < 4; ++i) {
      const int f4 = base + i * 131072;
      const float4 v = *(const float4*)(x + (size_t)f4 * 4);
      cvt_store4(Xhi + (size_t)f4 * 4, Xlo + (size_t)f4 * 4, v);
    }
  } else if (blk < 768) {
    const int q = blk - 512;
    const int k0 = (q & 15) * 64;
    const int n0 = ((q >> 4) & 7) * 64;
    const int cat = q >> 7;
    float (*lt)[72] = (float(*)[72])smem;
    const float* src = (cat == 0)
        ? (k0 < 512 ? Ws0 + (size_t)k0 * H_ : Wa0 + (size_t)(k0 - 512) * H_)
        : (k0 < 512 ? Ws1 + (size_t)k0 * H_ : Wa1 + (size_t)(k0 - 512) * H_);
    unsigned short* dhi = (cat == 0) ? W0thi : W1thi;
    unsigned short* dlo = (cat == 0) ? W0tlo : W1tlo;
#pragma unroll
    for (int i = 0; i < 4; ++i) {
      const int idx4 = t + 256 * i;
      const int kl = idx4 >> 4;
      const int n4 = (idx4 & 15) * 4;
      *(float4*)&lt[kl][n4] = *(const float4*)(src + (size_t)kl * H_ + n0 + n4);
    }
    __syncthreads();
#pragma unroll
    for (int i = 0; i < 4; ++i) {
      const int idx4 = t + 256 * i;
      const int nl = idx4 >> 4;
      const int k4 = (idx4 & 15) * 4;
      ushort4 h, l;
      const float v0 = lt[k4 + 0][nl], v1 = lt[k4 + 1][nl];
      const float v2 = lt[k4 + 2][nl], v3 = lt[k4 + 3][nl];
      h.x = f2bf(v0); l.x = f2bf(v0 - bf2f(h.x));
      h.y = f2bf(v1); l.y = f2bf(v1 - bf2f(h.y));
      h.z = f2bf(v2); l.z = f2bf(v2 - bf2f(h.z));
      h.w = f2bf(v3); l.w = f2bf(v3 - bf2f(h.w));
      *(ushort4*)(dhi + (size_t)(n0 + nl) * KA + k0 + k4) = h;
      *(ushort4*)(dlo + (size_t)(n0 + nl) * KA + k0 + k4) = l;
    }
  } else {
    const int q = blk - 768;
    const int b = q >> 2;
    const int nt0 = (q & 3) * 2;
    unsigned int* cnt = (unsigned int*)smem;               // [33][64]
    unsigned short* Cm = (unsigned short*)(smem + 8448);   // [48][64]
    unsigned short* XTh = (unsigned short*)(smem + 14592); // [64][72]
    unsigned short* XTl = XTh + 64 * 72;
    const int lane = t & 63;
    const int w = t >> 6;
    const int lr = lane & 15;
    const int kb8 = (lane >> 4) * 8;

#pragma unroll
    for (int i = 0; i < 9; ++i) { const int p = t + 256 * i; if (p < 2112) cnt[p] = 0u; }
#pragma unroll
    for (int i = 0; i < 12; ++i) Cm[t + 256 * i] = 0;
    __syncthreads();
#pragma unroll
    for (int i = 0; i < 4; ++i) {
      const int j = t + 256 * i;
      atomicAdd(&cnt[(j >> 5) * 64 + idx2[(size_t)b * 1024 + j]], 1u);
    }
    if (t < 32) atomicAdd(&cnt[32 * 64 + idx1[b * F_ + t]], 1u);
    __syncthreads();
#pragma unroll
    for (int i = 0; i < 9; ++i) {
      const int p = t + 256 * i;
      if (p < 2112) Cm[p] = f2bf((float)cnt[p] * 0.03125f);
    }
    __syncthreads();
    bf16x8 Af[3][2];
#pragma unroll
    for (int mi = 0; mi < 3; ++mi)
#pragma unroll
      for (int kt = 0; kt < 2; ++kt)
        Af[mi][kt] = *(const bf16x8*)&Cm[(mi * 16 + lr) * 64 + kt * 32 + kb8];

#pragma unroll
    for (int tt = 0; tt < 2; ++tt) {
      const int nbase = (nt0 + tt) * 64;
#pragma unroll
      for (int i = 0; i < 4; ++i) {
        const int f4 = t + 256 * i;
        const int l = f4 >> 4;
        const int c4 = (f4 & 15) * 4;
        const float4 v = *(const float4*)(x + (size_t)b * (L_ * D_) + (size_t)l * D_ + nbase + c4);
        unsigned short h;
        h = f2bf(v.x); XTh[(c4 + 0) * 72 + l] = h; XTl[(c4 + 0) * 72 + l] = f2bf(v.x - bf2f(h));
        h = f2bf(v.y); XTh[(c4 + 1) * 72 + l] = h; XTl[(c4 + 1) * 72 + l] = f2bf(v.y - bf2f(h));
        h = f2bf(v.z); XTh[(c4 + 2) * 72 + l] = h; XTl[(c4 + 2) * 72 + l] = f2bf(v.z - bf2f(h));
        h = f2bf(v.w); XTh[(c4 + 3) * 72 + l] = h; XTl[(c4 + 3) * 72 + l] = f2bf(v.w - bf2f(h));
      }
      __syncthreads();
      f32x4 acc[3] = {};
#pragma unroll
      for (int kt = 0; kt < 2; ++kt) {
        const bf16x8 Bh = *(const bf16x8*)&XTh[(w * 16 + lr) * 72 + kt * 32 + kb8];
        const bf16x8 Bl = *(const bf16x8*)&XTl[(w * 16 + lr) * 72 + kt * 32 + kb8];
#pragma unroll
        for (int mi = 0; mi < 3; ++mi) {
          acc[mi] = __builtin_amdgcn_mfma_f32_16x16x32_bf16(Af[mi][kt], Bh, acc[mi], 0, 0, 0);
          acc[mi] = __builtin_amdgcn_mfma_f32_16x16x32_bf16(Af[mi][kt], Bl, acc[mi], 0, 0, 0);
        }
      }
      const int col = nbase + w * 16 + lr;
#pragma unroll
      for (int mi = 0; mi < 3; ++mi)
#pragma unroll
        for (int r = 0; r < 4; ++r) {
          const int row48 = mi * 16 + (lane >> 4) * 4 + r;
          if (row48 > 32) continue;
          const size_t Mrow = (row48 < 32) ? (size_t)(b * F_ + row48) : (size_t)(M_ROWS + b);
          const float v = acc[mi][r];
          const unsigned short h = f2bf(v);
          Mh[Mrow * 512 + col] = h;
          Ml[Mrow * 512 + col] = f2bf(v - bf2f(h));
        }
      __syncthreads();
    }
  }
}

// ---------------- Kernel 2: gathered dbuf MFMA GEMM, 2-way split-K ----------
// R13 geometry (BM=64, BN=32, BK=64, 4 waves, 48KB dbuf LDS) with K=1024 split
// across 2 blocks: kc=0 -> X-gather half (W k<512), kc=1 -> M half (W k>=512).
// grid 1056 = 8 XCDs x 132, bijective. Combine via split-K semaphore; last
// arriver adds partner's fp32 partial (commutative, deterministic) and runs
// the R13 bias+leaky+mean epilogue.
__global__ __launch_bounds__(256) void gemm1(
    const unsigned short* __restrict__ Xhi, const unsigned short* __restrict__ Xlo,
    const unsigned short* __restrict__ Mh, const unsigned short* __restrict__ Ml,
    const unsigned short* __restrict__ Wthi, const unsigned short* __restrict__ Wtlo,
    const int* __restrict__ idx1, const float* __restrict__ b0,
    float* __restrict__ g1part, unsigned int* __restrict__ g1cnt,
    unsigned short* __restrict__ Hhi, unsigned short* __restrict__ Hlo) {
  __shared__ unsigned short lds[24576];  // 48 KB
  __shared__ int isLast;
  const int tid = threadIdx.x;
  const int lane = tid & 63;
  const int w = tid >> 6;
  const int wr = w >> 1, wc = w & 1;
  const int lr = lane & 15;
  const int kb = lane >> 4;
  const int swz = lr & 7;
  const int rsel = lane >> 3;
  const int cbs = ((lane & 7) ^ rsel) * 8;

  const int o = blockIdx.x;
  const int s = (o & 7) * 132 + (o >> 3);  // 1056 = 8 XCDs * 132, bijective
  const int kc = s & 1;
  const int s2 = s >> 1;                   // tile id 0..527
  const int bmi = s2 >> 4;                 // 0..32
  const int bni = s2 & 15;
  const int bm = bmi * 64;
  const int bn = bni * 32;

  int xrow[8];
  if (w < 2 && kc == 0) {
#pragma unroll
    for (int i = 0; i < 8; ++i) {
      const int R = bm + rsel + 8 * i;
      if (bmi < 32) xrow[i] = (R >> 5) * 64 + idx1[R];
      else          xrow[i] = (R - M_ROWS) * 64;  // f0 row of batch
    }
  }
  const unsigned short* Xp = (w == 0) ? Xhi : Xlo;
  const unsigned short* Mp = (w == 0) ? Mh : Ml;
  const unsigned short* Wp = (w == 2) ? Wthi : Wtlo;
  const unsigned short* mbase = Mp + (size_t)(bm + rsel) * 512 + cbs;
  const unsigned short* wbase = Wp + (size_t)(bn + rsel) * KA + kc * 512 + cbs;
  const int PB = (w == 0) ? 0 : (w == 1) ? 4096 : (w == 2) ? 8192 : 10240;

#define STAGE(KT, BUF)                                                        \
  {                                                                           \
    unsigned short* ldst = &lds[(BUF)*12288 + PB];                            \
    if (w < 2) {                                                              \
      if (kc == 0) {                                                          \
        const int co = (KT)*64 + cbs;                                         \
        _Pragma("unroll") for (int i = 0; i < 8; ++i)                         \
            GLOAD16(Xp + (size_t)xrow[i] * 512 + co, ldst + i * 512);         \
      } else {                                                                \
        const unsigned short* mb = mbase + (KT)*64;                           \
        _Pragma("unroll") for (int i = 0; i < 8; ++i)                         \
            GLOAD16(mb + (size_t)i * 8 * 512, ldst + i * 512);                \
      }                                                                       \
    } else {                                                                  \
      const unsigned short* wb = wbase + (KT)*64;                             \
      _Pragma("unroll") for (int i = 0; i < 4; ++i)                           \
          GLOAD16(wb + (size_t)i * 8 * KA, ldst + i * 512);                   \
    }                                                                         \
  }

  f32x4 acc[2] = {};
  STAGE(0, 0);
  __syncthreads();

#define AFRAG(PL, ROW, CB) \
  (*(const bf16x8*)&lds[buf * 12288 + (PL)*4096 + (ROW)*64 + (((CB) ^ swz) * 8)])
#define BFRAG(PL, ROW, CB) \
  (*(const bf16x8*)&lds[buf * 12288 + 8192 + (PL)*2048 + (ROW)*64 + (((CB) ^ swz) * 8)])

  for (int kt = 0; kt < 8; ++kt) {
    const int buf = kt & 1;
    if (kt < 7) STAGE(kt + 1, buf ^ 1);
#pragma unroll
    for (int ks = 0; ks < 2; ++ks) {
      const int c = ks * 4 + kb;
      const bf16x8 Ah0 = AFRAG(0, wr * 32 + lr, c);
      const bf16x8 Ah1 = AFRAG(0, wr * 32 + 16 + lr, c);
      const bf16x8 Al0 = AFRAG(1, wr * 32 + lr, c);
      const bf16x8 Al1 = AFRAG(1, wr * 32 + 16 + lr, c);
      const bf16x8 Bh = BFRAG(0, wc * 16 + lr, c);
      const bf16x8 Bl = BFRAG(1, wc * 16 + lr, c);
      acc[0] = __builtin_amdgcn_mfma_f32_16x16x32_bf16(Ah0, Bh, acc[0], 0, 0, 0);
      acc[0] = __builtin_amdgcn_mfma_f32_16x16x32_bf16(Ah0, Bl, acc[0], 0, 0, 0);
      acc[0] = __builtin_amdgcn_mfma_f32_16x16x32_bf16(Al0, Bh, acc[0], 0, 0, 0);
      acc[1] = __builtin_amdgcn_mfma_f32_16x16x32_bf16(Ah1, Bh, acc[1], 0, 0, 0);
      acc[1] = __builtin_amdgcn_mfma_f32_16x16x32_bf16(Ah1, Bl, acc[1], 0, 0, 0);
      acc[1] = __builtin_amdgcn_mfma_f32_16x16x32_bf16(Al1, Bh, acc[1], 0, 0, 0);
    }
    __syncthreads();
  }
#undef AFRAG
#undef BFRAG
#undef STAGE

  // ---- split-K combine: store own partial, arrive, last block finishes ----
  float* own = g1part + ((size_t)s2 * 2 + kc) * 2048;
#pragma unroll
  for (int mi = 0; mi < 2; ++mi)
#pragma unroll
    for (int r = 0; r < 4; ++r) {
      const int row = wr * 32 + mi * 16 + kb * 4 + r;
      own[row * 32 + wc * 16 + lr] = acc[mi][r];
    }
  __threadfence();
  __syncthreads();
  if (tid == 0) isLast = (atomicAdd(&g1cnt[s2], 1u) == 1u);
  __syncthreads();
  if (!isLast) return;
  __threadfence();

  const float* oth = g1part + ((size_t)s2 * 2 + (kc ^ 1)) * 2048;
  f32x4 z[2];
#pragma unroll
  for (int mi = 0; mi < 2; ++mi)
#pragma unroll
    for (int r = 0; r < 4; ++r) {
      const int row = wr * 32 + mi * 16 + kb * 4 + r;
      z[mi][r] = acc[mi][r] + oth[row * 32 + wc * 16 + lr];
    }

  // Epilogue (EXACT R13 math, acc -> z)
  const int col = bn + wc * 16 + lr;
  const float bias = b0[col];
  if (bmi < 32) {
    const int b = bmi * 2 + wr;
    float sum = 0.f;
#pragma unroll
    for (int mi = 0; mi < 2; ++mi)
#pragma unroll
      for (int r = 0; r < 4; ++r) sum += leaky(z[mi][r] + bias);
    sum += __shfl_xor(sum, 16);
    sum += __shfl_xor(sum, 32);
    sum *= (1.0f / 32.0f);
    if (lane < 16) {
      const unsigned short h = f2bf(sum);
      Hhi[(size_t)b * KA + 512 + col] = h;
      Hlo[(size_t)b * KA + 512 + col] = f2bf(sum - bf2f(h));
    }
  } else {
#pragma unroll
    for (int mi = 0; mi < 2; ++mi)
#pragma unroll
      for (int r = 0; r < 4; ++r) {
        const int b = wr * 32 + mi * 16 + kb * 4 + r;
        const float v = leaky(z[mi][r] + bias);
        const unsigned short h = f2bf(v);
        Hhi[(size_t)b * KA + col] = h;
        Hlo[(size_t)b * KA + col] = f2bf(v - bf2f(h));
      }
  }
}

// ---------------- Kernel 3: gemm2 split-K partials (EXACT R13) --------------
__global__ __launch_bounds__(256) void gemm2(
    const unsigned short* __restrict__ Hhi, const unsigned short* __restrict__ Hlo,
    const unsigned short* __restrict__ Wthi, const unsigned short* __restrict__ Wtlo,
    float* __restrict__ part) {
  __shared__ float sacc[256][17];
  const int tid = threadIdx.x;
  const int w = tid >> 6;
  const int lane = tid & 63;
  const int lr = lane & 15;
  const int kb = lane >> 4;
  const int n0 = blockIdx.x * 16;
  const int kc = blockIdx.y * 128;

  f32x4 acc[4] = {};
  const int k = kc + w * 32 + kb * 8;
  const bf16x8 Bh = *(const bf16x8*)(Wthi + (size_t)(n0 + lr) * KA + k);
  const bf16x8 Bl = *(const bf16x8*)(Wtlo + (size_t)(n0 + lr) * KA + k);
#pragma unroll
  for (int mi = 0; mi < 4; ++mi) {
    const bf16x8 Ah = *(const bf16x8*)(Hhi + (size_t)(mi * 16 + lr) * KA + k);
    const bf16x8 Al = *(const bf16x8*)(Hlo + (size_t)(mi * 16 + lr) * KA + k);
    acc[mi] = __builtin_amdgcn_mfma_f32_16x16x32_bf16(Ah, Bh, acc[mi], 0, 0, 0);
    acc[mi] = __builtin_amdgcn_mfma_f32_16x16x32_bf16(Ah, Bl, acc[mi], 0, 0, 0);
    acc[mi] = __builtin_amdgcn_mfma_f32_16x16x32_bf16(Al, Bh, acc[mi], 0, 0, 0);
  }
#pragma unroll
  for (int mi = 0; mi < 4; ++mi)
#pragma unroll
    for (int r = 0; r < 4; ++r)
      sacc[((w * 4 + mi) * 4 + kb) * 4 + r][lr] = acc[mi][r];
  __syncthreads();

  const int lr2 = tid & 15;
  const int rg = tid >> 4;
  float* pp = part + (size_t)blockIdx.y * (B_ * H_);
#pragma unroll
  for (int q = 0; q < 4; ++q) {
    const int row = rg * 4 + q;
    const int mi = row >> 4, kb2 = (row >> 2) & 3, r = row & 3;
    float sv = 0.f;
#pragma unroll
    for (int w2 = 0; w2 < 4; ++w2)
      sv += sacc[((w2 * 4 + mi) * 4 + kb2) * 4 + r][lr2];
    pp[(size_t)row * H_ + n0 + lr2] = sv;
  }
}

// ---------------- Kernel 4: out = sum_k part + b1 (EXACT R13) ---------------
__global__ __launch_bounds__(256) void reduce_out(
    const float* __restrict__ part, const float* __restrict__ b1,
    float* __restrict__ out) {
  const int idx = blockIdx.x * 256 + threadIdx.x;
  const int c4 = (idx & 127) * 4;
  const size_t off = (size_t)(idx >> 7) * H_ + c4;
  float4 s = *(const float4*)(b1 + c4);
#pragma unroll
  for (int ky = 0; ky < 8; ++ky) {
    const float4 p = *(const float4*)(part + (size_t)ky * (B_ * H_) + off);
    s.x += p.x; s.y += p.y; s.z += p.z; s.w += p.w;
  }
  *(float4*)(out + off) = s;
}

extern "C" void kernel_launch(void* const* d_in, const int* in_sizes, int n_in,
                              void* d_out, int out_size, void* d_ws, size_t ws_size,
                              hipStream_t stream) {
  const float* x    = (const float*)d_in[0];
  const int*   idx1 = (const int*)d_in[1];
  const int*   idx2 = (const int*)d_in[2];
  const float* Wa0  = (const float*)d_in[3];
  const float* b0   = (const float*)d_in[4];
  const float* Ws0  = (const float*)d_in[5];
  const float* Wa1  = (const float*)d_in[6];
  const float* b1   = (const float*)d_in[7];
  const float* Ws1  = (const float*)d_in[8];
  float* out = (float*)d_out;

  unsigned short* wsu = (unsigned short*)d_ws;
  unsigned short* Xhi   = wsu;                          // 4096*512
  unsigned short* Xlo   = Xhi + (size_t)4096 * 512;
  unsigned short* Mh    = Xlo + (size_t)4096 * 512;     // 2112*512
  unsigned short* Ml    = Mh + (size_t)M2 * 512;
  unsigned short* W0thi = Ml + (size_t)M2 * 512;        // [512][1024] each
  unsigned short* W0tlo = W0thi + (size_t)H_ * KA;
  unsigned short* W1thi = W0tlo + (size_t)H_ * KA;
  unsigned short* W1tlo = W1thi + (size_t)H_ * KA;
  unsigned short* Hhi   = W1tlo + (size_t)H_ * KA;      // 64*1024 each
  unsigned short* Hlo   = Hhi + (size_t)B_ * KA;
  float* part   = (float*)(Hlo + (size_t)B_ * KA);      // 8*64*512 fp32 (gemm2)
  float* g1part = part + (size_t)8 * B_ * H_;           // 528*2*2048 fp32
  unsigned int* g1cnt = (unsigned int*)(g1part + (size_t)528 * 2 * 2048);  // 528

  prep<<<1024, 256, 0, stream>>>(x, idx1, idx2, Ws0, Wa0, Ws1, Wa1,
                                 Xhi, Xlo, Mh, Ml, W0thi, W0tlo, W1thi, W1tlo,
                                 g1cnt);
  gemm1<<<1056, 256, 0, stream>>>(Xhi, Xlo, Mh, Ml, W0thi, W0tlo,
                                  idx1, b0, g1part, g1cnt, Hhi, Hlo);
  gemm2<<<dim3(32, 8), 256, 0, stream>>>(Hhi, Hlo, W1thi, W1tlo, part);
  reduce_out<<<32, 256, 0, stream>>>(part, b1, out);
}

// Round 16
// 36.313 us; speedup vs baseline: 4.8516x; 4.8516x over previous
//
#include <hip/hip_runtime.h>
#include <hip/hip_bf16.h>

// Shapes
#define B_ 64
#define L_ 64
#define D_ 512
#define F_ 32
#define H_ 512
#define M_ROWS 2048
#define M2 2112
#define KA 1024

typedef __attribute__((ext_vector_type(8))) short bf16x8;
typedef __attribute__((ext_vector_type(4))) float f32x4;

__device__ __forceinline__ float leaky(float v) { return v > 0.0f ? v : 0.01f * v; }

__device__ __forceinline__ unsigned short f2bf(float v) {
  unsigned int b = __float_as_uint(v);
  unsigned int r = b + 0x7FFF + ((b >> 16) & 1);  // RNE
  return (unsigned short)(r >> 16);
}
__device__ __forceinline__ float bf2f(unsigned short h) {
  return __uint_as_float(((unsigned int)h) << 16);
}
__device__ __forceinline__ void cvt_store4(unsigned short* ph, unsigned short* pl, float4 v) {
  ushort4 h, l;
  h.x = f2bf(v.x); l.x = f2bf(v.x - bf2f(h.x));
  h.y = f2bf(v.y); l.y = f2bf(v.y - bf2f(h.y));
  h.z = f2bf(v.z); l.z = f2bf(v.z - bf2f(h.z));
  h.w = f2bf(v.w); l.w = f2bf(v.w - bf2f(h.w));
  *(ushort4*)ph = h;
  *(ushort4*)pl = l;
}

#define GLOAD16(GP, LP)                                              \
  __builtin_amdgcn_global_load_lds(                                  \
      (const __attribute__((address_space(1))) unsigned int*)(GP),   \
      (__attribute__((address_space(3))) unsigned int*)(LP), 16, 0, 0)

// ---------------- Kernel 1: prep (EXACT R13 winner) ----------------
// blocks [0,512):    x-split flat (4 float4/thread) -> Xhi/Xlo [4096][512]
// blocks [512,768):  w-split
// blocks [768,1024): means
__global__ __launch_bounds__(256) void prep(
    const float* __restrict__ x, const int* __restrict__ idx1,
    const int* __restrict__ idx2,
    const float* __restrict__ Ws0, const float* __restrict__ Wa0,
    const float* __restrict__ Ws1, const float* __restrict__ Wa1,
    unsigned short* __restrict__ Xhi, unsigned short* __restrict__ Xlo,
    unsigned short* __restrict__ Mh, unsigned short* __restrict__ Ml,
    unsigned short* __restrict__ W0thi, unsigned short* __restrict__ W0tlo,
    unsigned short* __restrict__ W1thi, unsigned short* __restrict__ W1tlo) {
  __shared__ __align__(16) char smem[33024];
  const int blk = blockIdx.x;
  const int t = threadIdx.x;

  if (blk < 512) {
    const int base = blk * 256 + t;
#pragma unroll
    for (int i = 0; i < 4; ++i) {
      const int f4 = base + i * 131072;
      const float4 v = *(const float4*)(x + (size_t)f4 * 4);
      cvt_store4(Xhi + (size_t)f4 * 4, Xlo + (size_t)f4 * 4, v);
    }
  } else if (blk < 768) {
    const int q = blk - 512;
    const int k0 = (q & 15) * 64;
    const int n0 = ((q >> 4) & 7) * 64;
    const int cat = q >> 7;
    float (*lt)[72] = (float(*)[72])smem;
    const float* src = (cat == 0)
        ? (k0 < 512 ? Ws0 + (size_t)k0 * H_ : Wa0 + (size_t)(k0 - 512) * H_)
        : (k0 < 512 ? Ws1 + (size_t)k0 * H_ : Wa1 + (size_t)(k0 - 512) * H_);
    unsigned short* dhi = (cat == 0) ? W0thi : W1thi;
    unsigned short* dlo = (cat == 0) ? W0tlo : W1tlo;
#pragma unroll
    for (int i = 0; i < 4; ++i) {
      const int idx4 = t + 256 * i;
      const int kl = idx4 >> 4;
      const int n4 = (idx4 & 15) * 4;
      *(float4*)&lt[kl][n4] = *(const float4*)(src + (size_t)kl * H_ + n0 + n4);
    }
    __syncthreads();
#pragma unroll
    for (int i = 0; i < 4; ++i) {
      const int idx4 = t + 256 * i;
      const int nl = idx4 >> 4;
      const int k4 = (idx4 & 15) * 4;
      ushort4 h, l;
      const float v0 = lt[k4 + 0][nl], v1 = lt[k4 + 1][nl];
      const float v2 = lt[k4 + 2][nl], v3 = lt[k4 + 3][nl];
      h.x = f2bf(v0); l.x = f2bf(v0 - bf2f(h.x));
      h.y = f2bf(v1); l.y = f2bf(v1 - bf2f(h.y));
      h.z = f2bf(v2); l.z = f2bf(v2 - bf2f(h.z));
      h.w = f2bf(v3); l.w = f2bf(v3 - bf2f(h.w));
      *(ushort4*)(dhi + (size_t)(n0 + nl) * KA + k0 + k4) = h;
      *(ushort4*)(dlo + (size_t)(n0 + nl) * KA + k0 + k4) = l;
    }
  } else {
    const int q = blk - 768;
    const int b = q >> 2;
    const int nt0 = (q & 3) * 2;
    unsigned int* cnt = (unsigned int*)smem;               // [33][64]
    unsigned short* Cm = (unsigned short*)(smem + 8448);   // [48][64]
    unsigned short* XTh = (unsigned short*)(smem + 14592); // [64][72]
    unsigned short* XTl = XTh + 64 * 72;
    const int lane = t & 63;
    const int w = t >> 6;
    const int lr = lane & 15;
    const int kb8 = (lane >> 4) * 8;

#pragma unroll
    for (int i = 0; i < 9; ++i) { const int p = t + 256 * i; if (p < 2112) cnt[p] = 0u; }
#pragma unroll
    for (int i = 0; i < 12; ++i) Cm[t + 256 * i] = 0;
    __syncthreads();
#pragma unroll
    for (int i = 0; i < 4; ++i) {
      const int j = t + 256 * i;
      atomicAdd(&cnt[(j >> 5) * 64 + idx2[(size_t)b * 1024 + j]], 1u);
    }
    if (t < 32) atomicAdd(&cnt[32 * 64 + idx1[b * F_ + t]], 1u);
    __syncthreads();
#pragma unroll
    for (int i = 0; i < 9; ++i) {
      const int p = t + 256 * i;
      if (p < 2112) Cm[p] = f2bf((float)cnt[p] * 0.03125f);
    }
    __syncthreads();
    bf16x8 Af[3][2];
#pragma unroll
    for (int mi = 0; mi < 3; ++mi)
#pragma unroll
      for (int kt = 0; kt < 2; ++kt)
        Af[mi][kt] = *(const bf16x8*)&Cm[(mi * 16 + lr) * 64 + kt * 32 + kb8];

#pragma unroll
    for (int tt = 0; tt < 2; ++tt) {
      const int nbase = (nt0 + tt) * 64;
#pragma unroll
      for (int i = 0; i < 4; ++i) {
        const int f4 = t + 256 * i;
        const int l = f4 >> 4;
        const int c4 = (f4 & 15) * 4;
        const float4 v = *(const float4*)(x + (size_t)b * (L_ * D_) + (size_t)l * D_ + nbase + c4);
        unsigned short h;
        h = f2bf(v.x); XTh[(c4 + 0) * 72 + l] = h; XTl[(c4 + 0) * 72 + l] = f2bf(v.x - bf2f(h));
        h = f2bf(v.y); XTh[(c4 + 1) * 72 + l] = h; XTl[(c4 + 1) * 72 + l] = f2bf(v.y - bf2f(h));
        h = f2bf(v.z); XTh[(c4 + 2) * 72 + l] = h; XTl[(c4 + 2) * 72 + l] = f2bf(v.z - bf2f(h));
        h = f2bf(v.w); XTh[(c4 + 3) * 72 + l] = h; XTl[(c4 + 3) * 72 + l] = f2bf(v.w - bf2f(h));
      }
      __syncthreads();
      f32x4 acc[3] = {};
#pragma unroll
      for (int kt = 0; kt < 2; ++kt) {
        const bf16x8 Bh = *(const bf16x8*)&XTh[(w * 16 + lr) * 72 + kt * 32 + kb8];
        const bf16x8 Bl = *(const bf16x8*)&XTl[(w * 16 + lr) * 72 + kt * 32 + kb8];
#pragma unroll
        for (int mi = 0; mi < 3; ++mi) {
          acc[mi] = __builtin_amdgcn_mfma_f32_16x16x32_bf16(Af[mi][kt], Bh, acc[mi], 0, 0, 0);
          acc[mi] = __builtin_amdgcn_mfma_f32_16x16x32_bf16(Af[mi][kt], Bl, acc[mi], 0, 0, 0);
        }
      }
      const int col = nbase + w * 16 + lr;
#pragma unroll
      for (int mi = 0; mi < 3; ++mi)
#pragma unroll
        for (int r = 0; r < 4; ++r) {
          const int row48 = mi * 16 + (lane >> 4) * 4 + r;
          if (row48 > 32) continue;
          const size_t Mrow = (row48 < 32) ? (size_t)(b * F_ + row48) : (size_t)(M_ROWS + b);
          const float v = acc[mi][r];
          const unsigned short h = f2bf(v);
          Mh[Mrow * 512 + col] = h;
          Ml[Mrow * 512 + col] = f2bf(v - bf2f(h));
        }
      __syncthreads();
    }
  }
}

// ---------------- Kernel 2: gathered dbuf MFMA GEMM (EXACT R13 winner) ------
__global__ __launch_bounds__(256) void gemm1(
    const unsigned short* __restrict__ Xhi, const unsigned short* __restrict__ Xlo,
    const unsigned short* __restrict__ Mh, const unsigned short* __restrict__ Ml,
    const unsigned short* __restrict__ Wthi, const unsigned short* __restrict__ Wtlo,
    const int* __restrict__ idx1, const float* __restrict__ b0,
    unsigned short* __restrict__ Hhi, unsigned short* __restrict__ Hlo) {
  __shared__ unsigned short lds[24576];  // 48 KB
  const int tid = threadIdx.x;
  const int lane = tid & 63;
  const int w = tid >> 6;
  const int wr = w >> 1, wc = w & 1;
  const int lr = lane & 15;
  const int kb = lane >> 4;
  const int swz = lr & 7;
  const int rsel = lane >> 3;
  const int cbs = ((lane & 7) ^ rsel) * 8;

  const int o = blockIdx.x;
  const int s = (o & 7) * 66 + (o >> 3);  // 528 = 8 XCDs * 66, bijective
  const int bmi = s >> 4;
  const int bni = s & 15;
  const int bm = bmi * 64;
  const int bn = bni * 32;

  int xrow[8];
  if (w < 2) {
#pragma unroll
    for (int i = 0; i < 8; ++i) {
      const int R = bm + rsel + 8 * i;
      if (bmi < 32) xrow[i] = (R >> 5) * 64 + idx1[R];
      else          xrow[i] = (R - M_ROWS) * 64;  // f0 row of batch
    }
  }
  const unsigned short* Xp = (w == 0) ? Xhi : Xlo;
  const unsigned short* Mp = (w == 0) ? Mh : Ml;
  const unsigned short* Wp = (w == 2) ? Wthi : Wtlo;
  const unsigned short* mbase = Mp + (size_t)(bm + rsel) * 512 + cbs;
  const unsigned short* wbase = Wp + (size_t)(bn + rsel) * KA + cbs;
  const int PB = (w == 0) ? 0 : (w == 1) ? 4096 : (w == 2) ? 8192 : 10240;

#define STAGE(KT, BUF)                                                        \
  {                                                                           \
    unsigned short* ldst = &lds[(BUF)*12288 + PB];                            \
    if (w < 2) {                                                              \
      if ((KT) < 8) {                                                         \
        const int co = (KT)*64 + cbs;                                         \
        _Pragma("unroll") for (int i = 0; i < 8; ++i)                         \
            GLOAD16(Xp + (size_t)xrow[i] * 512 + co, ldst + i * 512);         \
      } else {                                                                \
        const unsigned short* mb = mbase + ((KT)-8) * 64;                     \
        _Pragma("unroll") for (int i = 0; i < 8; ++i)                         \
            GLOAD16(mb + (size_t)i * 8 * 512, ldst + i * 512);                \
      }                                                                       \
    } else {                                                                  \
      const unsigned short* wb = wbase + (KT)*64;                             \
      _Pragma("unroll") for (int i = 0; i < 4; ++i)                           \
          GLOAD16(wb + (size_t)i * 8 * KA, ldst + i * 512);                   \
    }                                                                         \
  }

  f32x4 acc[2] = {};
  STAGE(0, 0);
  __syncthreads();

#define AFRAG(PL, ROW, CB) \
  (*(const bf16x8*)&lds[buf * 12288 + (PL)*4096 + (ROW)*64 + (((CB) ^ swz) * 8)])
#define BFRAG(PL, ROW, CB) \
  (*(const bf16x8*)&lds[buf * 12288 + 8192 + (PL)*2048 + (ROW)*64 + (((CB) ^ swz) * 8)])

  for (int kt = 0; kt < 16; ++kt) {
    const int buf = kt & 1;
    if (kt < 15) STAGE(kt + 1, buf ^ 1);
#pragma unroll
    for (int ks = 0; ks < 2; ++ks) {
      const int c = ks * 4 + kb;
      const bf16x8 Ah0 = AFRAG(0, wr * 32 + lr, c);
      const bf16x8 Ah1 = AFRAG(0, wr * 32 + 16 + lr, c);
      const bf16x8 Al0 = AFRAG(1, wr * 32 + lr, c);
      const bf16x8 Al1 = AFRAG(1, wr * 32 + 16 + lr, c);
      const bf16x8 Bh = BFRAG(0, wc * 16 + lr, c);
      const bf16x8 Bl = BFRAG(1, wc * 16 + lr, c);
      acc[0] = __builtin_amdgcn_mfma_f32_16x16x32_bf16(Ah0, Bh, acc[0], 0, 0, 0);
      acc[0] = __builtin_amdgcn_mfma_f32_16x16x32_bf16(Ah0, Bl, acc[0], 0, 0, 0);
      acc[0] = __builtin_amdgcn_mfma_f32_16x16x32_bf16(Al0, Bh, acc[0], 0, 0, 0);
      acc[1] = __builtin_amdgcn_mfma_f32_16x16x32_bf16(Ah1, Bh, acc[1], 0, 0, 0);
      acc[1] = __builtin_amdgcn_mfma_f32_16x16x32_bf16(Ah1, Bl, acc[1], 0, 0, 0);
      acc[1] = __builtin_amdgcn_mfma_f32_16x16x32_bf16(Al1, Bh, acc[1], 0, 0, 0);
    }
    __syncthreads();
  }
#undef AFRAG
#undef BFRAG
#undef STAGE

  const int col = bn + wc * 16 + lr;
  const float bias = b0[col];
  if (bmi < 32) {
    const int b = bmi * 2 + wr;
    float sum = 0.f;
#pragma unroll
    for (int mi = 0; mi < 2; ++mi)
#pragma unroll
      for (int r = 0; r < 4; ++r) sum += leaky(acc[mi][r] + bias);
    sum += __shfl_xor(sum, 16);
    sum += __shfl_xor(sum, 32);
    sum *= (1.0f / 32.0f);
    if (lane < 16) {
      const unsigned short h = f2bf(sum);
      Hhi[(size_t)b * KA + 512 + col] = h;
      Hlo[(size_t)b * KA + 512 + col] = f2bf(sum - bf2f(h));
    }
  } else {
#pragma unroll
    for (int mi = 0; mi < 2; ++mi)
#pragma unroll
      for (int r = 0; r < 4; ++r) {
        const int b = wr * 32 + mi * 16 + kb * 4 + r;
        const float v = leaky(acc[mi][r] + bias);
        const unsigned short h = f2bf(v);
        Hhi[(size_t)b * KA + col] = h;
        Hlo[(size_t)b * KA + col] = f2bf(v - bf2f(h));
      }
  }
}

// ---------------- Kernel 3: gemm2 split-K partials (EXACT R13) --------------
__global__ __launch_bounds__(256) void gemm2(
    const unsigned short* __restrict__ Hhi, const unsigned short* __restrict__ Hlo,
    const unsigned short* __restrict__ Wthi, const unsigned short* __restrict__ Wtlo,
    float* __restrict__ part) {
  __shared__ float sacc[256][17];
  const int tid = threadIdx.x;
  const int w = tid >> 6;
  const int lane = tid & 63;
  const int lr = lane & 15;
  const int kb = lane >> 4;
  const int n0 = blockIdx.x * 16;
  const int kc = blockIdx.y * 128;

  f32x4 acc[4] = {};
  const int k = kc + w * 32 + kb * 8;
  const bf16x8 Bh = *(const bf16x8*)(Wthi + (size_t)(n0 + lr) * KA + k);
  const bf16x8 Bl = *(const bf16x8*)(Wtlo + (size_t)(n0 + lr) * KA + k);
#pragma unroll
  for (int mi = 0; mi < 4; ++mi) {
    const bf16x8 Ah = *(const bf16x8*)(Hhi + (size_t)(mi * 16 + lr) * KA + k);
    const bf16x8 Al = *(const bf16x8*)(Hlo + (size_t)(mi * 16 + lr) * KA + k);
    acc[mi] = __builtin_amdgcn_mfma_f32_16x16x32_bf16(Ah, Bh, acc[mi], 0, 0, 0);
    acc[mi] = __builtin_amdgcn_mfma_f32_16x16x32_bf16(Ah, Bl, acc[mi], 0, 0, 0);
    acc[mi] = __builtin_amdgcn_mfma_f32_16x16x32_bf16(Al, Bh, acc[mi], 0, 0, 0);
  }
#pragma unroll
  for (int mi = 0; mi < 4; ++mi)
#pragma unroll
    for (int r = 0; r < 4; ++r)
      sacc[((w * 4 + mi) * 4 + kb) * 4 + r][lr] = acc[mi][r];
  __syncthreads();

  const int lr2 = tid & 15;
  const int rg = tid >> 4;
  float* pp = part + (size_t)blockIdx.y * (B_ * H_);
#pragma unroll
  for (int q = 0; q < 4; ++q) {
    const int row = rg * 4 + q;
    const int mi = row >> 4, kb2 = (row >> 2) & 3, r = row & 3;
    float sv = 0.f;
#pragma unroll
    for (int w2 = 0; w2 < 4; ++w2)
      sv += sacc[((w2 * 4 + mi) * 4 + kb2) * 4 + r][lr2];
    pp[(size_t)row * H_ + n0 + lr2] = sv;
  }
}

// ---------------- Kernel 4: out = sum_k part + b1 (EXACT R13) ---------------
__global__ __launch_bounds__(256) void reduce_out(
    const float* __restrict__ part, const float* __restrict__ b1,
    float* __restrict__ out) {
  const int idx = blockIdx.x * 256 + threadIdx.x;
  const int c4 = (idx & 127) * 4;
  const size_t off = (size_t)(idx >> 7) * H_ + c4;
  float4 s = *(const float4*)(b1 + c4);
#pragma unroll
  for (int ky = 0; ky < 8; ++ky) {
    const float4 p = *(const float4*)(part + (size_t)ky * (B_ * H_) + off);
    s.x += p.x; s.y += p.y; s.z += p.z; s.w += p.w;
  }
  *(float4*)(out + off) = s;
}

extern "C" void kernel_launch(void* const* d_in, const int* in_sizes, int n_in,
                              void* d_out, int out_size, void* d_ws, size_t ws_size,
                              hipStream_t stream) {
  const float* x    = (const float*)d_in[0];
  const int*   idx1 = (const int*)d_in[1];
  const int*   idx2 = (const int*)d_in[2];
  const float* Wa0  = (const float*)d_in[3];
  const float* b0   = (const float*)d_in[4];
  const float* Ws0  = (const float*)d_in[5];
  const float* Wa1  = (const float*)d_in[6];
  const float* b1   = (const float*)d_in[7];
  const float* Ws1  = (const float*)d_in[8];
  float* out = (float*)d_out;

  unsigned short* wsu = (unsigned short*)d_ws;
  unsigned short* Xhi   = wsu;                          // 4096*512
  unsigned short* Xlo   = Xhi + (size_t)4096 * 512;
  unsigned short* Mh    = Xlo + (size_t)4096 * 512;     // 2112*512
  unsigned short* Ml    = Mh + (size_t)M2 * 512;
  unsigned short* W0thi = Ml + (size_t)M2 * 512;        // [512][1024] each
  unsigned short* W0tlo = W0thi + (size_t)H_ * KA;
  unsigned short* W1thi = W0tlo + (size_t)H_ * KA;
  unsigned short* W1tlo = W1thi + (size_t)H_ * KA;
  unsigned short* Hhi   = W1tlo + (size_t)H_ * KA;      // 64*1024 each
  unsigned short* Hlo   = Hhi + (size_t)B_ * KA;
  float* part = (float*)(Hlo + (size_t)B_ * KA);        // 8*64*512 fp32

  prep<<<1024, 256, 0, stream>>>(x, idx1, idx2, Ws0, Wa0, Ws1, Wa1,
                                 Xhi, Xlo, Mh, Ml, W0thi, W0tlo, W1thi, W1tlo);
  gemm1<<<528, 256, 0, stream>>>(Xhi, Xlo, Mh, Ml, W0thi, W0tlo,
                                 idx1, b0, Hhi, Hlo);
  gemm2<<<dim3(32, 8), 256, 0, stream>>>(Hhi, Hlo, W1thi, W1tlo, part);
  reduce_out<<<32, 256, 0, stream>>>(part, b1, out);
}